// Round 8
// baseline (1808.174 us; speedup 1.0000x reference)
//
#include <hip/hip_runtime.h>
#include <math.h>

#define NT 8192
#define DIM 7168
#define NE 256

#define TB 256   // tokens per block (lane = token)
#define TN 16    // experts per block = fp64 accumulators per lane
#define BK 16    // k-depth per LDS tile

// ws layout: [Wt fp64 DIM x NE = 14.68 MB][scores fp64 NT x NE = 16.78 MB]

// ---- pass 0: transpose + convert W [NE][DIM] f32 -> Wt [DIM][NE] f64 ----
__global__ __launch_bounds__(256) void wt_transpose(const float* __restrict__ w,
                                                    double* __restrict__ wt) {
    __shared__ float tile[32][33];
    const int kb = blockIdx.x * 32;   // DIM/32 = 224
    const int eb = blockIdx.y * 32;   // NE/32 = 8
    const int tx = (int)threadIdx.x & 31;
    const int ty = (int)threadIdx.x >> 5;  // 0..7
    #pragma unroll
    for (int r = 0; r < 4; ++r)       // coalesced read along k
        tile[ty + r * 8][tx] = w[(size_t)(eb + ty + r * 8) * DIM + kb + tx];
    __syncthreads();
    #pragma unroll
    for (int r = 0; r < 4; ++r)       // coalesced write along e
        wt[(size_t)(kb + ty + r * 8) * NE + eb + tx] = (double)tile[tx][ty + r * 8];
}

// ---- GEMM: scores = sigmoid(x @ W^T), fp64, scalar-pipe B ----
// lane = token. Per kk: 1 ds_read_b64 (A) + 16 v_fma_f64 with SGPR-pair B
// (wt index is wave-uniform -> s_load). LDS issue drops 0.5 -> 0.125 per FMA,
// turning the R5 LDS-issue bound (1175us) into a VALU bound (~383us floor).
// Same k-ascending fp64 fma order as R5 -> bitwise-identical scores.
__global__ __launch_bounds__(256) void gate_gemm_f64(const float* __restrict__ x,
                                                     const double* __restrict__ wt,
                                                     double* __restrict__ scores) {
    __shared__ double As[BK][TB];            // 32 KB, k-major
    const int tbk = blockIdx.x;              // 0..31 (fast axis: x stays L3-hot)
    const int ebk = blockIdx.y;              // 0..15
    const int t = (int)threadIdx.x;
    const int ts = t >> 2;                   // staging token row 0..63 (+64r)
    const int kc = (t & 3) << 2;             // staging k offset 0,4,8,12

    const float* xg = x + (size_t)(tbk * TB) * DIM;

    double acc[TN];
    #pragma unroll
    for (int e = 0; e < TN; ++e) acc[e] = 0.0;

    float4 pv[4];                            // register prefetch of tile kb
    #pragma unroll
    for (int r = 0; r < 4; ++r)
        pv[r] = *(const float4*)(xg + (size_t)(ts + r * 64) * DIM + kc);

    for (int kb = 0; kb < DIM; kb += BK) {
        __syncthreads();
        #pragma unroll
        for (int r = 0; r < 4; ++r) {        // stage fp64, k-major
            const int tok = ts + r * 64;
            As[kc + 0][tok] = (double)pv[r].x;
            As[kc + 1][tok] = (double)pv[r].y;
            As[kc + 2][tok] = (double)pv[r].z;
            As[kc + 3][tok] = (double)pv[r].w;
        }
        __syncthreads();
        if (kb + BK < DIM) {                 // prefetch next tile (uniform branch)
            #pragma unroll
            for (int r = 0; r < 4; ++r)
                pv[r] = *(const float4*)(xg + (size_t)(ts + r * 64) * DIM + kb + BK + kc);
        }
        const double* __restrict__ wrow = wt + (size_t)kb * NE + ebk * TN;
        #pragma unroll 2
        for (int kk = 0; kk < BK; ++kk) {
            const double a = As[kk][t];      // lane's token value at k
            const double* __restrict__ br = wrow + (size_t)kk * NE;  // uniform -> s_load
            #pragma unroll
            for (int e = 0; e < TN; ++e)
                acc[e] = fma(a, br[e], acc[e]);
        }
    }
    // epilogue: sigmoid; per-lane 128B contiguous store (full cachelines)
    double* srow = scores + (size_t)(tbk * TB + t) * NE + ebk * TN;
    #pragma unroll
    for (int e = 0; e < TN; ++e)
        srow[e] = 1.0 / (1.0 + exp(-acc[e]));
}

// ---------------- Routing: one wave (64 lanes) per token, fp64 ----------------
__global__ __launch_bounds__(256) void gate_route_f64(const double* __restrict__ scores,
                                                      const float* __restrict__ bias,
                                                      float* __restrict__ out) {
    const int t = (int)threadIdx.x;
    const int lane = t & 63;
    const int token = blockIdx.x * 4 + (t >> 6);

    const double4 sc4 = *(const double4*)&scores[(size_t)token * NE + lane * 4];
    const float4 bi4 = *(const float4*)&bias[lane * 4];
    const double orig[4] = {sc4.x, sc4.y, sc4.z, sc4.w};
    const double sb[4] = {orig[0] + (double)bi4.x, orig[1] + (double)bi4.y,
                          orig[2] + (double)bi4.z, orig[3] + (double)bi4.w};

    // per-lane top-2 of 4 (values only)
    const double m1 = fmax(sb[0], sb[1]), m2 = fmin(sb[0], sb[1]);
    const double m3 = fmax(sb[2], sb[3]), m4 = fmin(sb[2], sb[3]);
    double hi = fmax(m1, m3);
    double lo = fmax(fmin(m1, m3), fmax(m2, m4));
    #pragma unroll
    for (int off = 1; off < 8; off <<= 1) {  // merge top-2 across the 8-lane group
        const double oh = __shfl_xor(hi, off);
        const double ol = __shfl_xor(lo, off);
        const double nhi = fmax(hi, oh);
        const double nlo = fmax(fmin(hi, oh), fmax(lo, ol));
        hi = nhi; lo = nlo;
    }
    const double gsum = hi + lo;
    const int g = lane >> 3;

    int rank = 0;                            // group rank (desc, low idx wins ties)
    #pragma unroll
    for (int j = 0; j < 8; ++j) {
        const double gj = __shfl(gsum, j * 8);
        rank += (gj > gsum) || (gj == gsum && j < g);
    }
    const bool sel = rank < 4;

    double mv[4];                            // unselected groups exactly 0.0
    #pragma unroll
    for (int i = 0; i < 4; ++i) mv[i] = sel ? sb[i] : 0.0;

    double wsel[8];
    int isel[8];
    double wsum = 0.0;
    #pragma unroll
    for (int r = 0; r < 8; ++r) {
        double v = mv[0]; int ii = 0;        // local argmax (low idx wins ties)
        if (mv[1] > v) { v = mv[1]; ii = 1; }
        if (mv[2] > v) { v = mv[2]; ii = 2; }
        if (mv[3] > v) { v = mv[3]; ii = 3; }
        int idx = lane * 4 + ii;
        #pragma unroll
        for (int off = 1; off < 64; off <<= 1) {  // wave argmax butterfly
            const double ov = __shfl_xor(v, off);
            const int    oi = __shfl_xor(idx, off);
            if (ov > v || (ov == v && oi < idx)) { v = ov; idx = oi; }
        }
        const int owner = idx >> 2, slot = idx & 3;
        const double os = (slot == 0) ? orig[0] : (slot == 1) ? orig[1]
                        : (slot == 2) ? orig[2] : orig[3];
        const double ow = __shfl(os, owner);      // ORIGINAL (un-biased) score
        wsel[r] = ow; isel[r] = idx; wsum += ow;
        if (lane == owner) {
            if      (slot == 0) mv[0] = -INFINITY;
            else if (slot == 1) mv[1] = -INFINITY;
            else if (slot == 2) mv[2] = -INFINITY;
            else                mv[3] = -INFINITY;
        }
    }

    if (lane == 0) {
        const double scale = 2.5 / wsum;
        #pragma unroll
        for (int r = 0; r < 8; ++r) {
            out[(size_t)token * 8 + r] = (float)(wsel[r] * scale);          // weights
            out[(size_t)NT * 8 + (size_t)token * 8 + r] = (float)isel[r];  // idx as f32
        }
    }
}

extern "C" void kernel_launch(void* const* d_in, const int* in_sizes, int n_in,
                              void* d_out, int out_size, void* d_ws, size_t ws_size,
                              hipStream_t stream) {
    const float* x    = (const float*)d_in[0];
    // d_in[1] = token_mask (all ones; unused by the reference math)
    const float* w    = (const float*)d_in[2];
    const float* bias = (const float*)d_in[3];
    float* out = (float*)d_out;

    double* wt     = (double*)d_ws;                 // 14.68 MB
    double* scores = wt + (size_t)DIM * NE;         // 16.78 MB

    wt_transpose<<<dim3(DIM / 32, NE / 32), 256, 0, stream>>>(w, wt);
    gate_gemm_f64<<<dim3(NT / TB, NE / TN), 256, 0, stream>>>(x, wt, scores);
    gate_route_f64<<<NT / 4, 256, 0, stream>>>(scores, bias, out);
}